// Round 4
// baseline (915.774 us; speedup 1.0000x reference)
//
#include <hip/hip_runtime.h>

// ---------------------------------------------------------------------------
// Transformer-XL decoder layer on MI355X (gfx950).
// QLEN=1024, MLEN=1024, KLEN=2048, BSZ=4, DMODEL=1024, NHEAD=16, DHEAD=64, DFF=4096
// Round 4: attention made barrier-free. Each WAVE owns a 16-row i-tile and
// reads K/V^T/R MFMA B-fragments directly from global (L2-resident 256 KB
// slabs; 16x64B segments per instruction). Only the P C->A-layout round trip
// uses LDS (wave-private). No __syncthreads in the kernel at all.
// rel_shift fact: BD[i,j] = BDu[i, j+1023-i] for j <= i+1024; rest is masked.
// ---------------------------------------------------------------------------

typedef __bf16 bf16x8 __attribute__((ext_vector_type(8)));
typedef float f32x4 __attribute__((ext_vector_type(4)));

#define DEVI __device__ __forceinline__

DEVI unsigned short f2bf(float f) {
  union { float f; unsigned int u; } v;
  v.f = f;
  unsigned int u = v.u;
  u += 0x7fffu + ((u >> 16) & 1u);  // RNE
  return (unsigned short)(u >> 16);
}

// async global->LDS, 16 B per lane; lds dest must be the wave-uniform base
// (HW writes base + lane*16). Per-lane global address from VGPR.
DEVI void load16(const unsigned short* g, unsigned short* l) {
  __builtin_amdgcn_global_load_lds(
      (const __attribute__((address_space(1))) unsigned int*)g,
      (__attribute__((address_space(3))) unsigned int*)l, 16, 0, 0);
}

// ---------------------------------------------------------------------------
// f32 -> bf16 elementwise convert (grid covers exactly n/4 float4 groups)
// ---------------------------------------------------------------------------
__global__ __launch_bounds__(256) void cvt_bf16_kernel(const float* __restrict__ in,
                                                       unsigned short* __restrict__ out) {
  const int i = blockIdx.x * 256 + threadIdx.x;
  float4 v = *(const float4*)(in + (size_t)i * 4);
  ushort4 o;
  o.x = f2bf(v.x);
  o.y = f2bf(v.y);
  o.z = f2bf(v.z);
  o.w = f2bf(v.w);
  *(ushort4*)(out + (size_t)i * 4) = o;
}

// ---------------------------------------------------------------------------
// transpose + convert to bf16: out[c][r] = bf16(in[r][c]); batched via blockIdx.z
// ---------------------------------------------------------------------------
template <typename T>
__global__ __launch_bounds__(256) void transpose_to_bf16(
    const T* __restrict__ in, unsigned short* __restrict__ out, int R, int C) {
  __shared__ unsigned short t[64][72];
  const int tid = threadIdx.x;
  const size_t zoff = (size_t)blockIdx.z * R * C;
  const int r0 = blockIdx.y * 64, c0 = blockIdx.x * 64;
  const T* inp = in + zoff;
  unsigned short* outp = out + zoff;
#pragma unroll
  for (int it = 0; it < 4; ++it) {
    int f = tid + 256 * it;          // 1024 groups of 4 elements
    int r = f >> 4;
    int c4 = (f & 15) << 2;
    if constexpr (sizeof(T) == 4) {
      float4 v = *(const float4*)((const float*)inp + (size_t)(r0 + r) * C + c0 + c4);
      t[c4 + 0][r] = f2bf(v.x);
      t[c4 + 1][r] = f2bf(v.y);
      t[c4 + 2][r] = f2bf(v.z);
      t[c4 + 3][r] = f2bf(v.w);
    } else {
      ushort4 v = *(const ushort4*)((const unsigned short*)inp + (size_t)(r0 + r) * C + c0 + c4);
      t[c4 + 0][r] = v.x;
      t[c4 + 1][r] = v.y;
      t[c4 + 2][r] = v.z;
      t[c4 + 3][r] = v.w;
    }
  }
  __syncthreads();
#pragma unroll
  for (int it = 0; it < 4; ++it) {
    int f = tid + 256 * it;
    int cc = f >> 4;
    int r4 = (f & 15) << 2;
    ushort4 o;
    o.x = t[cc][r4 + 0];
    o.y = t[cc][r4 + 1];
    o.z = t[cc][r4 + 2];
    o.w = t[cc][r4 + 3];
    *(ushort4*)(outp + (size_t)(c0 + cc) * R + r0 + r4) = o;
  }
}

// ---------------------------------------------------------------------------
// 128x128x64 MFMA GEMM, global_load_lds staging. A row-major bf16 [M][K],
// B pre-transposed bf16 [N][K]. Unpadded LDS tiles [128][64] with XOR chunk
// swizzle: lds[row][c] holds global 16B-chunk (c ^ (row&7)).
// 256 thr = 4 waves, each wave a 64x64 quadrant (4x4 tiles of 16x16x32 MFMA).
// EPI 0: QKV scatter; EPI 1: R scatter; EPI 2: bias/resid/relu -> f32/bf16.
// ---------------------------------------------------------------------------
struct GemmArgs {
  const unsigned short* A;   // bf16 [M][K]
  const unsigned short* Bt;  // bf16 [N][K]
  int row_split;             // EPI0: rows below this skip q columns
  int M, N, K;
  const float* p0;  // bias_q (EPI0) / bias (EPI2)
  const float* p1;  // bias_k (EPI0)
  const float* resid;
  float* outF;
  unsigned short* o0;  // QQ / Rb / bf16-out
  unsigned short* o1;  // QK
  unsigned short* o2;  // Kb
  unsigned short* o3;  // Vb
  int relu;
};

constexpr int BM = 128, BN = 128, BK = 64;

template <int EPI>
__global__ __launch_bounds__(256, 4) void gemm_kernel(GemmArgs ga) {
  __shared__ __align__(16) unsigned short As[BM * BK];
  __shared__ __align__(16) unsigned short Bs[BN * BK];

  const int n0 = blockIdx.x * BN;
  const int m0 = blockIdx.y * BM;
  if constexpr (EPI == 0) {
    // q-columns for memory rows are discarded by the reference
    if (n0 + BN <= 1024 && m0 + BM <= ga.row_split) return;
  }
  const int tid = threadIdx.x;
  const int lane = tid & 63;
  const int wv = tid >> 6;
  const int l15 = lane & 15;
  const int quad = lane >> 4;
  const int wm = wv & 1, wn = wv >> 1;
  const int K = ga.K;
  const int r8 = lane >> 3;       // row within 8-row issue
  const int sc = (lane & 7) ^ r8; // swizzled source chunk

  const f32x4 fzero = {0.f, 0.f, 0.f, 0.f};
  f32x4 acc[4][4];
#pragma unroll
  for (int i = 0; i < 4; ++i)
#pragma unroll
    for (int j = 0; j < 4; ++j) acc[i][j] = fzero;

  const unsigned short* Ab = ga.A + (size_t)(m0 + 32 * wv + r8) * K + sc * 8;
  const unsigned short* Bb = ga.Bt + (size_t)(n0 + 32 * wv + r8) * K + sc * 8;
  const int h7 = l15 & 7;

  for (int k0 = 0; k0 < K; k0 += BK) {
    __syncthreads();
#pragma unroll
    for (int it = 0; it < 4; ++it)
      load16(Ab + (size_t)(8 * it) * K + k0, &As[(32 * wv + 8 * it) * 64]);
#pragma unroll
    for (int it = 0; it < 4; ++it)
      load16(Bb + (size_t)(8 * it) * K + k0, &Bs[(32 * wv + 8 * it) * 64]);
    __syncthreads();
#pragma unroll
    for (int ks = 0; ks < 2; ++ks) {
      bf16x8 af[4], bg[4];
#pragma unroll
      for (int mt = 0; mt < 4; ++mt)
        af[mt] = *(const bf16x8*)&As[(wm * 64 + mt * 16 + l15) * 64 +
                                     (((ks * 4 + quad) ^ h7) * 8)];
#pragma unroll
      for (int nt = 0; nt < 4; ++nt)
        bg[nt] = *(const bf16x8*)&Bs[(wn * 64 + nt * 16 + l15) * 64 +
                                     (((ks * 4 + quad) ^ h7) * 8)];
#pragma unroll
      for (int mt = 0; mt < 4; ++mt)
#pragma unroll
        for (int nt = 0; nt < 4; ++nt)
          acc[mt][nt] =
              __builtin_amdgcn_mfma_f32_16x16x32_bf16(af[mt], bg[nt], acc[mt][nt], 0, 0, 0);
    }
  }

  // epilogue; C/D layout: row = quad*4+reg, col = lane&15
#pragma unroll
  for (int mt = 0; mt < 4; ++mt) {
#pragma unroll
    for (int nt = 0; nt < 4; ++nt) {
#pragma unroll
      for (int r = 0; r < 4; ++r) {
        const int row = m0 + wm * 64 + mt * 16 + quad * 4 + r;
        const int col = n0 + wn * 64 + nt * 16 + l15;
        float val = acc[mt][nt][r];
        if constexpr (EPI == 0) {
          const int seq = row >> 2, b = row & 3;  // cat flat row = seq*BSZ + b
          if (col < 1024) {
            if (seq >= 1024) {
              const int nh = col >> 6, d = col & 63;
              const size_t o = ((size_t)((b * 16 + nh) * 1024 + (seq - 1024))) * 64 + d;
              ga.o0[o] = f2bf(val + ga.p0[col]);  // q + bias_q
              ga.o1[o] = f2bf(val + ga.p1[col]);  // q + bias_k
            }
          } else if (col < 2048) {
            const int c = col - 1024, nh = c >> 6, d = c & 63;
            ga.o2[((size_t)((b * 16 + nh) * 2048 + seq)) * 64 + d] = f2bf(val);
          } else {
            const int c = col - 2048, nh = c >> 6, d = c & 63;
            ga.o3[((size_t)((b * 16 + nh) * 2048 + seq)) * 64 + d] = f2bf(val);
          }
        } else if constexpr (EPI == 1) {
          const int nh = col >> 6, d = col & 63;
          ga.o0[((size_t)(nh * 2048 + row)) * 64 + d] = f2bf(val);
        } else {
          if (ga.p0) val += ga.p0[col];
          if (ga.resid) val += ga.resid[(size_t)row * ga.N + col];
          if (ga.relu) val = fmaxf(val, 0.f);
          if (ga.outF) ga.outF[(size_t)row * ga.N + col] = val;
          if (ga.o0) ga.o0[(size_t)row * ga.N + col] = f2bf(val);
        }
      }
    }
  }
}

// ---------------------------------------------------------------------------
// Flash attention with Transformer-XL relative-position term (v4).
// Barrier-free: one wave per 16-row i-tile; K/V^T/R B-fragments read directly
// from global (L2-resident per-(b,n) slabs; each read = 16 rows x 64 B).
// Fixed-max softmax: p = exp2((AC+BD)*0.125*log2e); masked -> 0 via select;
// l reduced once at epilogue. Only P's C->A-layout hop uses (wave-private) LDS.
// ---------------------------------------------------------------------------
constexpr int P_LD = 136;  // p_s row stride in bf16 elems (272 B)
constexpr float CEXP = 0.18033688f;  // 0.125 * log2(e)

__global__ __launch_bounds__(256, 3) void attn_kernel(
    const unsigned short* __restrict__ QQ, const unsigned short* __restrict__ QK,
    const unsigned short* __restrict__ Kb, const unsigned short* __restrict__ Vt,
    const unsigned short* __restrict__ Rb, unsigned short* __restrict__ AVb) {
  __shared__ __align__(16) unsigned short p_s[4][16 * P_LD];

  const int tid = threadIdx.x;
  const int lane = tid & 63;
  const int wv = tid >> 6;
  const int l15 = lane & 15;
  const int quad = lane >> 4;
  const int i0 = (blockIdx.x * 4 + wv) * 16;  // wave-private 16-row i-tile
  const int bn = blockIdx.y;
  const int nh = bn & 15;
  const int bb = bn >> 4;
  unsigned short* pw = &p_s[wv][0];

  const unsigned short* kp = Kb + (size_t)bn * (2048 * 64);
  const unsigned short* vtp = Vt + (size_t)bn * (64 * 2048);
  const unsigned short* rp = Rb + (size_t)nh * (2048 * 64);

  // Q fragments in registers: rows [i0, i0+16)
  const size_t qoff = (size_t)bn * (1024 * 64) + (size_t)(i0 + l15) * 64;
  const bf16x8 qq0 = *(const bf16x8*)(QQ + qoff + quad * 8);
  const bf16x8 qq1 = *(const bf16x8*)(QQ + qoff + 32 + quad * 8);
  const bf16x8 qk0 = *(const bf16x8*)(QK + qoff + quad * 8);
  const bf16x8 qk1 = *(const bf16x8*)(QK + qoff + 32 + quad * 8);

  const f32x4 fzero = {0.f, 0.f, 0.f, 0.f};
  f32x4 o_acc[4];
#pragma unroll
  for (int i = 0; i < 4; ++i) o_acc[i] = fzero;
  float lsum[4] = {0.f, 0.f, 0.f, 0.f};

  const int jmax = i0 + 15 + 1024;  // beyond this, tiles are fully masked
  for (int j0 = 0; j0 <= jmax; j0 += 128) {
    // BDu over the 144-wide R window starting at tb (9 col-tiles of 16).
    const int tb = j0 + 1008 - i0;  // window base; >= 0 always
    f32x4 bd[9];
#pragma unroll
    for (int ct = 0; ct < 9; ++ct) {
      int t = tb + ct * 16 + l15;
      t = (t < 2047) ? t : 2047;  // clamp: rows >=2048 only feed masked cols
      const unsigned short* rrow = rp + (size_t)t * 64;
      bf16x8 b0 = *(const bf16x8*)(rrow + quad * 8);
      bf16x8 b1 = *(const bf16x8*)(rrow + 32 + quad * 8);
      f32x4 c = fzero;
      c = __builtin_amdgcn_mfma_f32_16x16x32_bf16(qk0, b0, c, 0, 0, 0);
      c = __builtin_amdgcn_mfma_f32_16x16x32_bf16(qk1, b1, c, 0, 0, 0);
      bd[ct] = c;
    }

    // AC = (q+bias_q) @ K^T, K fragments direct from global
    float sv[8][4];
#pragma unroll
    for (int nt = 0; nt < 8; ++nt) {
      const unsigned short* krow = kp + (size_t)(j0 + nt * 16 + l15) * 64;
      bf16x8 b0 = *(const bf16x8*)(krow + quad * 8);
      bf16x8 b1 = *(const bf16x8*)(krow + 32 + quad * 8);
      f32x4 c = fzero;
      c = __builtin_amdgcn_mfma_f32_16x16x32_bf16(qq0, b0, c, 0, 0, 0);
      c = __builtin_amdgcn_mfma_f32_16x16x32_bf16(qq1, b1, c, 0, 0, 0);
#pragma unroll
      for (int r = 0; r < 4; ++r) sv[nt][r] = c[r];
    }

    // rel-shift (in-quad rotate) + fixed-max exp + per-lane l accumulation
#pragma unroll
    for (int r = 0; r < 4; ++r) {
      const int il = quad * 4 + r;  // tile-local row
      const int u = l15 + 15 - il;  // 0..30
      const int srcl = (lane & 48) | (u & 15);
      float w[9];
#pragma unroll
      for (int ct = 0; ct < 9; ++ct) w[ct] = __shfl(bd[ct][r], srcl, 64);
      const int ig = i0 + il;
#pragma unroll
      for (int nt = 0; nt < 8; ++nt) {
        const float bdv = (u & 16) ? w[nt + 1] : w[nt];
        const int jg = j0 + nt * 16 + l15;
        float p = exp2f((sv[nt][r] + bdv) * CEXP);
        p = (jg > ig + 1024) ? 0.f : p;  // select: garbage/NaN-safe
        lsum[r] += p;
        pw[il * P_LD + nt * 16 + l15] = f2bf(p);
      }
    }

    // O += P @ V (K-dim = 128, 4 k-steps); P from wave-private LDS,
    // V^T fragments direct from global.
#pragma unroll
    for (int ks = 0; ks < 4; ++ks) {
      bf16x8 ap = *(const bf16x8*)&pw[l15 * P_LD + ks * 32 + quad * 8];
#pragma unroll
      for (int nto = 0; nto < 4; ++nto) {
        bf16x8 bv = *(const bf16x8*)(vtp + (size_t)(nto * 16 + l15) * 2048 + j0 +
                                     ks * 32 + quad * 8);
        o_acc[nto] = __builtin_amdgcn_mfma_f32_16x16x32_bf16(ap, bv, o_acc[nto], 0, 0, 0);
      }
    }
  }

  // reduce l across the 16 lanes holding each row, then write O/l
  float linv[4];
#pragma unroll
  for (int r = 0; r < 4; ++r) {
    float l = lsum[r];
    l += __shfl_xor(l, 1, 64);
    l += __shfl_xor(l, 2, 64);
    l += __shfl_xor(l, 4, 64);
    l += __shfl_xor(l, 8, 64);
    linv[r] = 1.f / l;
  }
#pragma unroll
  for (int nto = 0; nto < 4; ++nto) {
#pragma unroll
    for (int r = 0; r < 4; ++r) {
      const int ig = i0 + quad * 4 + r;
      const int d = nto * 16 + l15;
      const float val = o_acc[nto][r] * linv[r];
      AVb[(size_t)(ig * 4 + bb) * 1024 + nh * 64 + d] = f2bf(val);
    }
  }
}

// ---------------------------------------------------------------------------
// LayerNorm over rows of 1024; optional f32 and bf16 outputs.
// ---------------------------------------------------------------------------
__global__ __launch_bounds__(256) void ln_kernel(const float* __restrict__ x,
                                                 const float* __restrict__ g,
                                                 const float* __restrict__ bta,
                                                 float* __restrict__ outF,
                                                 unsigned short* __restrict__ outB) {
  const int row = blockIdx.x;
  const int tid = threadIdx.x;
  const float* xr = x + (size_t)row * 1024;
  const float4 v = *(const float4*)(xr + tid * 4);
  float s = v.x + v.y + v.z + v.w;
  float ss = v.x * v.x + v.y * v.y + v.z * v.z + v.w * v.w;
#pragma unroll
  for (int off = 1; off < 64; off <<= 1) {
    s += __shfl_xor(s, off, 64);
    ss += __shfl_xor(ss, off, 64);
  }
  __shared__ float red[8];
  const int wv = tid >> 6;
  if ((tid & 63) == 0) {
    red[wv] = s;
    red[4 + wv] = ss;
  }
  __syncthreads();
  s = red[0] + red[1] + red[2] + red[3];
  ss = red[4] + red[5] + red[6] + red[7];
  const float mu = s * (1.f / 1024.f);
  const float var = ss * (1.f / 1024.f) - mu * mu;
  const float rs = rsqrtf(var + 1e-5f);
  const float vv[4] = {v.x, v.y, v.z, v.w};
#pragma unroll
  for (int u = 0; u < 4; ++u) {
    const int c = tid * 4 + u;
    const float y = (vv[u] - mu) * rs * g[c] + bta[c];
    if (outF) outF[(size_t)row * 1024 + c] = y;
    if (outB) outB[(size_t)row * 1024 + c] = f2bf(y);
  }
}

// ---------------------------------------------------------------------------
extern "C" void kernel_launch(void* const* d_in, const int* in_sizes, int n_in,
                              void* d_out, int out_size, void* d_ws, size_t ws_size,
                              hipStream_t stream) {
  (void)in_sizes; (void)n_in; (void)out_size; (void)ws_size;
  const float* word_embed = (const float*)d_in[0];
  const float* pos_embed = (const float*)d_in[1];
  const float* bias_q = (const float*)d_in[2];
  const float* bias_k = (const float*)d_in[3];
  const float* memories = (const float*)d_in[4];
  const float* W_qkv = (const float*)d_in[5];
  const float* W_r = (const float*)d_in[6];
  const float* W_o = (const float*)d_in[7];
  const float* ln1_g = (const float*)d_in[8];
  const float* ln1_b = (const float*)d_in[9];
  const float* W_ff1 = (const float*)d_in[10];
  const float* b_ff1 = (const float*)d_in[11];
  const float* W_ff2 = (const float*)d_in[12];
  const float* b_ff2 = (const float*)d_in[13];
  const float* ln2_g = (const float*)d_in[14];
  const float* ln2_b = (const float*)d_in[15];
  // d_in[16] = attention_mask: causal-with-memory, computed analytically in-kernel
  float* out = (float*)d_out;

  char* ws = (char*)d_ws;
  unsigned short* QQ = (unsigned short*)(ws + 0);           // 8 MB
  unsigned short* QK = (unsigned short*)(ws + 8388608);     // 8 MB
  unsigned short* Kb = (unsigned short*)(ws + 16777216);    // 16 MB
  unsigned short* Vb = (unsigned short*)(ws + 33554432);    // 16 MB
  unsigned short* Vt = (unsigned short*)(ws + 50331648);    // 16 MB
  unsigned short* Rb = (unsigned short*)(ws + 67108864);    // 4 MB
  unsigned short* AVb = (unsigned short*)(ws + 71303168);   // 8 MB
  float* X1 = (float*)(ws + 79691776);                      // 16 MB (also C2)
  float* OUT1 = (float*)(ws + 96468992);                    // 16 MB
  unsigned short* OUT1b = (unsigned short*)(ws + 113246208);  // 8 MB
  unsigned short* Wqkv_t = (unsigned short*)(ws + 121634816); // 6 MB
  unsigned short* Wr_t = (unsigned short*)(ws + 127926272);   // 2 MB
  unsigned short* Wo_t = (unsigned short*)(ws + 130023424);   // 2 MB
  unsigned short* Wff1_t = (unsigned short*)(ws + 132120576); // 8 MB
  unsigned short* Wff2_t = (unsigned short*)(ws + 140509184); // 8 MB
  // Catb aliases X1 (dead until Wo GEMM); Posb aliases OUT1 (dead until LN1).
  unsigned short* Catb = (unsigned short*)(ws + 79691776);    // 16 MB, [8192][1024]
  unsigned short* Posb = (unsigned short*)(ws + 96468992);    // 4 MB, [2048][1024]
  // H aliases [0, 33554432): QQ/QK/Kb are dead after attention
  unsigned short* H = (unsigned short*)(ws + 0);
  float* C2 = X1;  // X1 dead after LN1

  const dim3 blk(256);

  // 0. activation converts: cat(memories, word_embed) and pos_embed -> bf16
  cvt_bf16_kernel<<<4096, blk, 0, stream>>>(memories, Catb);
  cvt_bf16_kernel<<<4096, blk, 0, stream>>>(word_embed, Catb + (size_t)4096 * 1024);
  cvt_bf16_kernel<<<2048, blk, 0, stream>>>(pos_embed, Posb);

  // 1. weight transposes (f32 [R][C] -> bf16 [C][R])
  transpose_to_bf16<float><<<dim3(48, 16, 1), blk, 0, stream>>>(W_qkv, Wqkv_t, 1024, 3072);
  transpose_to_bf16<float><<<dim3(16, 16, 1), blk, 0, stream>>>(W_r, Wr_t, 1024, 1024);
  transpose_to_bf16<float><<<dim3(16, 16, 1), blk, 0, stream>>>(W_o, Wo_t, 1024, 1024);
  transpose_to_bf16<float><<<dim3(64, 16, 1), blk, 0, stream>>>(W_ff1, Wff1_t, 1024, 4096);
  transpose_to_bf16<float><<<dim3(16, 64, 1), blk, 0, stream>>>(W_ff2, Wff2_t, 4096, 1024);

  // 2. QKV projection: M=8192, N=3072, K=1024
  {
    GemmArgs a{};
    a.A = Catb;
    a.row_split = 4096;
    a.Bt = Wqkv_t;
    a.M = 8192; a.N = 3072; a.K = 1024;
    a.p0 = bias_q; a.p1 = bias_k;
    a.o0 = QQ; a.o1 = QK; a.o2 = Kb; a.o3 = Vb;
    gemm_kernel<0><<<dim3(24, 64), blk, 0, stream>>>(a);
  }
  // 3. R projection: M=2048, N=1024, K=1024
  {
    GemmArgs a{};
    a.A = Posb;
    a.Bt = Wr_t;
    a.M = 2048; a.N = 1024; a.K = 1024;
    a.o0 = Rb;
    gemm_kernel<1><<<dim3(8, 16), blk, 0, stream>>>(a);
  }
  // 4. V transpose per (b,n) slab: [2048][64] -> [64][2048]
  transpose_to_bf16<unsigned short><<<dim3(1, 32, 64), blk, 0, stream>>>(Vb, Vt, 2048, 64);

  // 5. attention (one wave per 16-row i-tile; 64 i-tiles x 64 bn)
  attn_kernel<<<dim3(16, 64), blk, 0, stream>>>(QQ, QK, Kb, Vt, Rb, AVb);

  // 6. W_o projection + residual: M=4096, N=1024, K=1024
  {
    GemmArgs a{};
    a.A = AVb;
    a.Bt = Wo_t;
    a.M = 4096; a.N = 1024; a.K = 1024;
    a.resid = word_embed;
    a.outF = X1;
    gemm_kernel<2><<<dim3(8, 32), blk, 0, stream>>>(a);
  }
  ln_kernel<<<4096, blk, 0, stream>>>(X1, ln1_g, ln1_b, OUT1, OUT1b);

  // 7. FFN
  {
    GemmArgs a{};
    a.A = OUT1b;
    a.Bt = Wff1_t;
    a.M = 4096; a.N = 4096; a.K = 1024;
    a.p0 = b_ff1;
    a.relu = 1;
    a.o0 = H;
    gemm_kernel<2><<<dim3(32, 32), blk, 0, stream>>>(a);
  }
  {
    GemmArgs a{};
    a.A = H;
    a.Bt = Wff2_t;
    a.M = 4096; a.N = 1024; a.K = 4096;
    a.p0 = b_ff2;
    a.resid = OUT1;
    a.outF = C2;
    gemm_kernel<2><<<dim3(8, 32), blk, 0, stream>>>(a);
  }
  // 8. final LN -> output
  ln_kernel<<<4096, blk, 0, stream>>>(C2, ln2_g, ln2_b, out, nullptr);
}

// Round 5
// 737.282 us; speedup vs baseline: 1.2421x; 1.2421x over previous
//
#include <hip/hip_runtime.h>

// ---------------------------------------------------------------------------
// Transformer-XL decoder layer on MI355X (gfx950).
// QLEN=1024, MLEN=1024, KLEN=2048, BSZ=4, DMODEL=1024, NHEAD=16, DHEAD=64, DFF=4096
// Round 5: attention = R3 LDS-staged structure + (a) 32-row waves (2 sub-tiles
// per wave, B-fragment reuse, shared BD window reads), (b) double-buffered
// K/V^T/R tiles with cross-tile async prefetch -> ONE barrier per j-tile,
// (c) 145 KB LDS, 1 block/CU. GEMMs unchanged from R3.
// rel_shift fact: BD[i,j] = BDu[i, j+1023-i] for j <= i+1024; rest is masked.
// ---------------------------------------------------------------------------

typedef __bf16 bf16x8 __attribute__((ext_vector_type(8)));
typedef float f32x4 __attribute__((ext_vector_type(4)));

#define DEVI __device__ __forceinline__

DEVI unsigned short f2bf(float f) {
  union { float f; unsigned int u; } v;
  v.f = f;
  unsigned int u = v.u;
  u += 0x7fffu + ((u >> 16) & 1u);  // RNE
  return (unsigned short)(u >> 16);
}

// async global->LDS, 16 B per lane; lds dest is the wave-uniform base
// (HW writes base + lane*16).
DEVI void load16(const unsigned short* g, unsigned short* l) {
  __builtin_amdgcn_global_load_lds(
      (const __attribute__((address_space(1))) unsigned int*)g,
      (__attribute__((address_space(3))) unsigned int*)l, 16, 0, 0);
}

// ---------------------------------------------------------------------------
// f32 -> bf16 elementwise convert (grid covers exactly n/4 float4 groups)
// ---------------------------------------------------------------------------
__global__ __launch_bounds__(256) void cvt_bf16_kernel(const float* __restrict__ in,
                                                       unsigned short* __restrict__ out) {
  const int i = blockIdx.x * 256 + threadIdx.x;
  float4 v = *(const float4*)(in + (size_t)i * 4);
  ushort4 o;
  o.x = f2bf(v.x);
  o.y = f2bf(v.y);
  o.z = f2bf(v.z);
  o.w = f2bf(v.w);
  *(ushort4*)(out + (size_t)i * 4) = o;
}

// ---------------------------------------------------------------------------
// transpose + convert to bf16: out[c][r] = bf16(in[r][c]); batched via blockIdx.z
// ---------------------------------------------------------------------------
template <typename T>
__global__ __launch_bounds__(256) void transpose_to_bf16(
    const T* __restrict__ in, unsigned short* __restrict__ out, int R, int C) {
  __shared__ unsigned short t[64][72];
  const int tid = threadIdx.x;
  const size_t zoff = (size_t)blockIdx.z * R * C;
  const int r0 = blockIdx.y * 64, c0 = blockIdx.x * 64;
  const T* inp = in + zoff;
  unsigned short* outp = out + zoff;
#pragma unroll
  for (int it = 0; it < 4; ++it) {
    int f = tid + 256 * it;          // 1024 groups of 4 elements
    int r = f >> 4;
    int c4 = (f & 15) << 2;
    if constexpr (sizeof(T) == 4) {
      float4 v = *(const float4*)((const float*)inp + (size_t)(r0 + r) * C + c0 + c4);
      t[c4 + 0][r] = f2bf(v.x);
      t[c4 + 1][r] = f2bf(v.y);
      t[c4 + 2][r] = f2bf(v.z);
      t[c4 + 3][r] = f2bf(v.w);
    } else {
      ushort4 v = *(const ushort4*)((const unsigned short*)inp + (size_t)(r0 + r) * C + c0 + c4);
      t[c4 + 0][r] = v.x;
      t[c4 + 1][r] = v.y;
      t[c4 + 2][r] = v.z;
      t[c4 + 3][r] = v.w;
    }
  }
  __syncthreads();
#pragma unroll
  for (int it = 0; it < 4; ++it) {
    int f = tid + 256 * it;
    int cc = f >> 4;
    int r4 = (f & 15) << 2;
    ushort4 o;
    o.x = t[cc][r4 + 0];
    o.y = t[cc][r4 + 1];
    o.z = t[cc][r4 + 2];
    o.w = t[cc][r4 + 3];
    *(ushort4*)(outp + (size_t)(c0 + cc) * R + r0 + r4) = o;
  }
}

// ---------------------------------------------------------------------------
// 128x128x64 MFMA GEMM, global_load_lds staging (unchanged from R3).
// ---------------------------------------------------------------------------
struct GemmArgs {
  const unsigned short* A;   // bf16 [M][K]
  const unsigned short* Bt;  // bf16 [N][K]
  int row_split;             // EPI0: rows below this skip q columns
  int M, N, K;
  const float* p0;  // bias_q (EPI0) / bias (EPI2)
  const float* p1;  // bias_k (EPI0)
  const float* resid;
  float* outF;
  unsigned short* o0;  // QQ / Rb / bf16-out
  unsigned short* o1;  // QK
  unsigned short* o2;  // Kb
  unsigned short* o3;  // Vb
  int relu;
};

constexpr int BM = 128, BN = 128, BK = 64;

template <int EPI>
__global__ __launch_bounds__(256, 4) void gemm_kernel(GemmArgs ga) {
  __shared__ __align__(16) unsigned short As[BM * BK];
  __shared__ __align__(16) unsigned short Bs[BN * BK];

  const int n0 = blockIdx.x * BN;
  const int m0 = blockIdx.y * BM;
  if constexpr (EPI == 0) {
    if (n0 + BN <= 1024 && m0 + BM <= ga.row_split) return;
  }
  const int tid = threadIdx.x;
  const int lane = tid & 63;
  const int wv = tid >> 6;
  const int l15 = lane & 15;
  const int quad = lane >> 4;
  const int wm = wv & 1, wn = wv >> 1;
  const int K = ga.K;
  const int r8 = lane >> 3;
  const int sc = (lane & 7) ^ r8;

  const f32x4 fzero = {0.f, 0.f, 0.f, 0.f};
  f32x4 acc[4][4];
#pragma unroll
  for (int i = 0; i < 4; ++i)
#pragma unroll
    for (int j = 0; j < 4; ++j) acc[i][j] = fzero;

  const unsigned short* Ab = ga.A + (size_t)(m0 + 32 * wv + r8) * K + sc * 8;
  const unsigned short* Bb = ga.Bt + (size_t)(n0 + 32 * wv + r8) * K + sc * 8;
  const int h7 = l15 & 7;

  for (int k0 = 0; k0 < K; k0 += BK) {
    __syncthreads();
#pragma unroll
    for (int it = 0; it < 4; ++it)
      load16(Ab + (size_t)(8 * it) * K + k0, &As[(32 * wv + 8 * it) * 64]);
#pragma unroll
    for (int it = 0; it < 4; ++it)
      load16(Bb + (size_t)(8 * it) * K + k0, &Bs[(32 * wv + 8 * it) * 64]);
    __syncthreads();
#pragma unroll
    for (int ks = 0; ks < 2; ++ks) {
      bf16x8 af[4], bg[4];
#pragma unroll
      for (int mt = 0; mt < 4; ++mt)
        af[mt] = *(const bf16x8*)&As[(wm * 64 + mt * 16 + l15) * 64 +
                                     (((ks * 4 + quad) ^ h7) * 8)];
#pragma unroll
      for (int nt = 0; nt < 4; ++nt)
        bg[nt] = *(const bf16x8*)&Bs[(wn * 64 + nt * 16 + l15) * 64 +
                                     (((ks * 4 + quad) ^ h7) * 8)];
#pragma unroll
      for (int mt = 0; mt < 4; ++mt)
#pragma unroll
        for (int nt = 0; nt < 4; ++nt)
          acc[mt][nt] =
              __builtin_amdgcn_mfma_f32_16x16x32_bf16(af[mt], bg[nt], acc[mt][nt], 0, 0, 0);
    }
  }

#pragma unroll
  for (int mt = 0; mt < 4; ++mt) {
#pragma unroll
    for (int nt = 0; nt < 4; ++nt) {
#pragma unroll
      for (int r = 0; r < 4; ++r) {
        const int row = m0 + wm * 64 + mt * 16 + quad * 4 + r;
        const int col = n0 + wn * 64 + nt * 16 + l15;
        float val = acc[mt][nt][r];
        if constexpr (EPI == 0) {
          const int seq = row >> 2, b = row & 3;
          if (col < 1024) {
            if (seq >= 1024) {
              const int nh = col >> 6, d = col & 63;
              const size_t o = ((size_t)((b * 16 + nh) * 1024 + (seq - 1024))) * 64 + d;
              ga.o0[o] = f2bf(val + ga.p0[col]);
              ga.o1[o] = f2bf(val + ga.p1[col]);
            }
          } else if (col < 2048) {
            const int c = col - 1024, nh = c >> 6, d = c & 63;
            ga.o2[((size_t)((b * 16 + nh) * 2048 + seq)) * 64 + d] = f2bf(val);
          } else {
            const int c = col - 2048, nh = c >> 6, d = c & 63;
            ga.o3[((size_t)((b * 16 + nh) * 2048 + seq)) * 64 + d] = f2bf(val);
          }
        } else if constexpr (EPI == 1) {
          const int nh = col >> 6, d = col & 63;
          ga.o0[((size_t)(nh * 2048 + row)) * 64 + d] = f2bf(val);
        } else {
          if (ga.p0) val += ga.p0[col];
          if (ga.resid) val += ga.resid[(size_t)row * ga.N + col];
          if (ga.relu) val = fmaxf(val, 0.f);
          if (ga.outF) ga.outF[(size_t)row * ga.N + col] = val;
          if (ga.o0) ga.o0[(size_t)row * ga.N + col] = f2bf(val);
        }
      }
    }
  }
}

// ---------------------------------------------------------------------------
// Flash attention with Transformer-XL relative-position term (v5).
// Block = 128 i-rows (4 waves x 32 rows, 2 sub-tiles each). j-tiles of 128,
// double-buffered K/V^T/R staging with cross-tile prefetch; one barrier/tile.
// BD window: 256 shared R rows; per wave, 10 16-row positions shared between
// its 2 sub-tiles (shifted by one position). Fixed-max softmax, l reduced at
// epilogue. P goes through wave-private 16-row LDS slots; PV per sub-tile.
// LDS = 145 KB -> 1 block/CU.
// ---------------------------------------------------------------------------
constexpr int P_LD = 136;            // p_s row stride (bf16 elems)
constexpr float CEXP = 0.18033688f;  // 0.125 * log2(e)

__global__ __launch_bounds__(256, 1) void attn_kernel(
    const unsigned short* __restrict__ QQ, const unsigned short* __restrict__ QK,
    const unsigned short* __restrict__ Kb, const unsigned short* __restrict__ Vt,
    const unsigned short* __restrict__ Rb, unsigned short* __restrict__ AVb) {
  __shared__ __align__(16) unsigned short kt_s[2][128 * 64];
  __shared__ __align__(16) unsigned short vt_s[2][64 * 128];
  __shared__ __align__(16) unsigned short r_s[2][256 * 64];
  __shared__ __align__(16) unsigned short p_s[4][16 * P_LD];

  const int tid = threadIdx.x;
  const int lane = tid & 63;
  const int wv = tid >> 6;
  const int l15 = lane & 15;
  const int quad = lane >> 4;
  const int h7 = l15 & 7;
  const int i0 = blockIdx.x * 128;
  const int iw = i0 + 32 * wv;  // wave's 32 rows
  const int bn = blockIdx.y;
  const int nh = bn & 15;
  const int bb = bn >> 4;
  const int r8 = lane >> 3;
  const int sc = (lane & 7) ^ r8;  // swizzled chunk for 8-chunk (64-elem) rows
  const int r4 = lane >> 4;
  const int c16 = lane & 15;
  unsigned short* pw = &p_s[wv][0];

  const unsigned short* kp = Kb + (size_t)bn * (2048 * 64);
  const unsigned short* vtp = Vt + (size_t)bn * (64 * 2048);
  const unsigned short* rp = Rb + (size_t)nh * (2048 * 64);

  // Q fragments for both sub-tiles (rows iw+16*mt .. +16)
  bf16x8 qq0[2], qq1[2], qk0[2], qk1[2];
#pragma unroll
  for (int mt = 0; mt < 2; ++mt) {
    const size_t qo = (size_t)bn * (1024 * 64) + (size_t)(iw + 16 * mt + l15) * 64;
    qq0[mt] = *(const bf16x8*)(QQ + qo + quad * 8);
    qq1[mt] = *(const bf16x8*)(QQ + qo + 32 + quad * 8);
    qk0[mt] = *(const bf16x8*)(QK + qo + quad * 8);
    qk1[mt] = *(const bf16x8*)(QK + qo + 32 + quad * 8);
  }

  const f32x4 fzero = {0.f, 0.f, 0.f, 0.f};
  f32x4 o_acc[2][4];
#pragma unroll
  for (int mt = 0; mt < 2; ++mt)
#pragma unroll
    for (int i = 0; i < 4; ++i) o_acc[mt][i] = fzero;
  float lsum[2][4] = {{0.f, 0.f, 0.f, 0.f}, {0.f, 0.f, 0.f, 0.f}};

  const int T = ((i0 + 1151) >> 7) + 1;  // j-tiles; last unmasked j = i0+127+1024

  // staging: 16 global_load_lds issues per wave per tile
#define ISSUE_TILE(t_, b_)                                                            \
  {                                                                                   \
    const int j0_ = (t_) << 7;                                                        \
    _Pragma("unroll") for (int it = 0; it < 4; ++it)                                  \
        load16(kp + (size_t)(j0_ + 32 * wv + 8 * it + r8) * 64 + sc * 8,              \
               &kt_s[b_][(32 * wv + 8 * it) * 64]);                                   \
    _Pragma("unroll") for (int it = 0; it < 4; ++it) {                                \
      const int d_ = 16 * wv + 4 * it + r4;                                           \
      load16(vtp + (size_t)d_ * 2048 + j0_ + ((c16 ^ (d_ & 15)) * 8),                 \
             &vt_s[b_][(16 * wv + 4 * it) * 128]);                                    \
    }                                                                                 \
    const int rb0_ = j0_ - i0 + 896;                                                  \
    _Pragma("unroll") for (int it = 0; it < 8; ++it)                                  \
        load16(rp + (size_t)(rb0_ + 64 * wv + 8 * it + r8) * 64 + sc * 8,             \
               &r_s[b_][(64 * wv + 8 * it) * 64]);                                    \
  }

  ISSUE_TILE(0, 0)

  for (int t = 0; t < T; ++t) {
    __syncthreads();  // drains tile t's loads (issued a full compute phase ago)
    if (t + 1 < T) ISSUE_TILE(t + 1, (t + 1) & 1)
    const int b = t & 1;
    const int j0 = t << 7;
    const unsigned short* kt = kt_s[b];
    const unsigned short* vt = vt_s[b];
    const unsigned short* rs = r_s[b];

    // AC = (q+bias_q) @ K^T for both sub-tiles (B-fragments shared)
    f32x4 sv[2][8];
#pragma unroll
    for (int nt = 0; nt < 8; ++nt) {
      const int kr = nt * 16 + l15;
      bf16x8 b0 = *(const bf16x8*)&kt[kr * 64 + ((quad ^ h7) * 8)];
      bf16x8 b1 = *(const bf16x8*)&kt[kr * 64 + (((4 + quad) ^ h7) * 8)];
#pragma unroll
      for (int mt = 0; mt < 2; ++mt) {
        f32x4 c = fzero;
        c = __builtin_amdgcn_mfma_f32_16x16x32_bf16(qq0[mt], b0, c, 0, 0, 0);
        c = __builtin_amdgcn_mfma_f32_16x16x32_bf16(qq1[mt], b1, c, 0, 0, 0);
        sv[mt][nt] = c;
      }
    }

    // BDu: 10 shared window positions; sub-tile 1 uses ct=p, sub-tile 0 ct=p-1.
    f32x4 bd[2][9];
    const int pbase = 96 - 32 * wv;  // r_s row base of position 0 for this wave
#pragma unroll
    for (int p = 0; p < 10; ++p) {
      const int tr = pbase + p * 16 + l15;
      bf16x8 b0 = *(const bf16x8*)&rs[tr * 64 + ((quad ^ h7) * 8)];
      bf16x8 b1 = *(const bf16x8*)&rs[tr * 64 + (((4 + quad) ^ h7) * 8)];
      if (p < 9) {
        f32x4 c = fzero;
        c = __builtin_amdgcn_mfma_f32_16x16x32_bf16(qk0[1], b0, c, 0, 0, 0);
        c = __builtin_amdgcn_mfma_f32_16x16x32_bf16(qk1[1], b1, c, 0, 0, 0);
        bd[1][p] = c;
      }
      if (p >= 1) {
        f32x4 c = fzero;
        c = __builtin_amdgcn_mfma_f32_16x16x32_bf16(qk0[0], b0, c, 0, 0, 0);
        c = __builtin_amdgcn_mfma_f32_16x16x32_bf16(qk1[0], b1, c, 0, 0, 0);
        bd[0][p - 1] = c;
      }
    }

    // per sub-tile: rel-shift (in-quad rotate) + exp + P write + PV
#pragma unroll
    for (int mt = 0; mt < 2; ++mt) {
#pragma unroll
      for (int r = 0; r < 4; ++r) {
        const int il = quad * 4 + r;
        const int u = l15 + 15 - il;  // 0..30
        const int srcl = (lane & 48) | (u & 15);
        float w[9];
#pragma unroll
        for (int ct = 0; ct < 9; ++ct) w[ct] = __shfl(bd[mt][ct][r], srcl, 64);
        const int ig = iw + 16 * mt + il;
#pragma unroll
        for (int nt = 0; nt < 8; ++nt) {
          const float bdv = (u & 16) ? w[nt + 1] : w[nt];
          const int jg = j0 + nt * 16 + l15;
          float p = exp2f((sv[mt][nt][r] + bdv) * CEXP);
          p = (jg > ig + 1024) ? 0.f : p;  // select: garbage/NaN-safe
          lsum[mt][r] += p;
          pw[il * P_LD + nt * 16 + l15] = f2bf(p);
        }
      }
      // PV for this sub-tile (wave-private p_s slot; DS ops in-order per wave)
#pragma unroll
      for (int ks = 0; ks < 4; ++ks) {
        bf16x8 ap = *(const bf16x8*)&pw[l15 * P_LD + ks * 32 + quad * 8];
#pragma unroll
        for (int nto = 0; nto < 4; ++nto) {
          bf16x8 bv = *(const bf16x8*)&vt[(nto * 16 + l15) * 128 +
                                          (((ks * 4 + quad) ^ l15) * 8)];
          o_acc[mt][nto] =
              __builtin_amdgcn_mfma_f32_16x16x32_bf16(ap, bv, o_acc[mt][nto], 0, 0, 0);
        }
      }
    }
  }
#undef ISSUE_TILE

  // reduce l across the 16 lanes holding each row, then write O/l
#pragma unroll
  for (int mt = 0; mt < 2; ++mt) {
    float linv[4];
#pragma unroll
    for (int r = 0; r < 4; ++r) {
      float l = lsum[mt][r];
      l += __shfl_xor(l, 1, 64);
      l += __shfl_xor(l, 2, 64);
      l += __shfl_xor(l, 4, 64);
      l += __shfl_xor(l, 8, 64);
      linv[r] = 1.f / l;
    }
#pragma unroll
    for (int nto = 0; nto < 4; ++nto) {
#pragma unroll
      for (int r = 0; r < 4; ++r) {
        const int ig = iw + 16 * mt + quad * 4 + r;
        const int d = nto * 16 + l15;
        const float val = o_acc[mt][nto][r] * linv[r];
        AVb[(size_t)(ig * 4 + bb) * 1024 + nh * 64 + d] = f2bf(val);
      }
    }
  }
}

// ---------------------------------------------------------------------------
// LayerNorm over rows of 1024; optional f32 and bf16 outputs.
// ---------------------------------------------------------------------------
__global__ __launch_bounds__(256) void ln_kernel(const float* __restrict__ x,
                                                 const float* __restrict__ g,
                                                 const float* __restrict__ bta,
                                                 float* __restrict__ outF,
                                                 unsigned short* __restrict__ outB) {
  const int row = blockIdx.x;
  const int tid = threadIdx.x;
  const float* xr = x + (size_t)row * 1024;
  const float4 v = *(const float4*)(xr + tid * 4);
  float s = v.x + v.y + v.z + v.w;
  float ss = v.x * v.x + v.y * v.y + v.z * v.z + v.w * v.w;
#pragma unroll
  for (int off = 1; off < 64; off <<= 1) {
    s += __shfl_xor(s, off, 64);
    ss += __shfl_xor(ss, off, 64);
  }
  __shared__ float red[8];
  const int wv = tid >> 6;
  if ((tid & 63) == 0) {
    red[wv] = s;
    red[4 + wv] = ss;
  }
  __syncthreads();
  s = red[0] + red[1] + red[2] + red[3];
  ss = red[4] + red[5] + red[6] + red[7];
  const float mu = s * (1.f / 1024.f);
  const float var = ss * (1.f / 1024.f) - mu * mu;
  const float rs = rsqrtf(var + 1e-5f);
  const float vv[4] = {v.x, v.y, v.z, v.w};
#pragma unroll
  for (int u = 0; u < 4; ++u) {
    const int c = tid * 4 + u;
    const float y = (vv[u] - mu) * rs * g[c] + bta[c];
    if (outF) outF[(size_t)row * 1024 + c] = y;
    if (outB) outB[(size_t)row * 1024 + c] = f2bf(y);
  }
}

// ---------------------------------------------------------------------------
extern "C" void kernel_launch(void* const* d_in, const int* in_sizes, int n_in,
                              void* d_out, int out_size, void* d_ws, size_t ws_size,
                              hipStream_t stream) {
  (void)in_sizes; (void)n_in; (void)out_size; (void)ws_size;
  const float* word_embed = (const float*)d_in[0];
  const float* pos_embed = (const float*)d_in[1];
  const float* bias_q = (const float*)d_in[2];
  const float* bias_k = (const float*)d_in[3];
  const float* memories = (const float*)d_in[4];
  const float* W_qkv = (const float*)d_in[5];
  const float* W_r = (const float*)d_in[6];
  const float* W_o = (const float*)d_in[7];
  const float* ln1_g = (const float*)d_in[8];
  const float* ln1_b = (const float*)d_in[9];
  const float* W_ff1 = (const float*)d_in[10];
  const float* b_ff1 = (const float*)d_in[11];
  const float* W_ff2 = (const float*)d_in[12];
  const float* b_ff2 = (const float*)d_in[13];
  const float* ln2_g = (const float*)d_in[14];
  const float* ln2_b = (const float*)d_in[15];
  float* out = (float*)d_out;

  char* ws = (char*)d_ws;
  unsigned short* QQ = (unsigned short*)(ws + 0);           // 8 MB
  unsigned short* QK = (unsigned short*)(ws + 8388608);     // 8 MB
  unsigned short* Kb = (unsigned short*)(ws + 16777216);    // 16 MB
  unsigned short* Vb = (unsigned short*)(ws + 33554432);    // 16 MB
  unsigned short* Vt = (unsigned short*)(ws + 50331648);    // 16 MB
  unsigned short* Rb = (unsigned short*)(ws + 67108864);    // 4 MB
  unsigned short* AVb = (unsigned short*)(ws + 71303168);   // 8 MB
  float* X1 = (float*)(ws + 79691776);                      // 16 MB (also C2)
  float* OUT1 = (float*)(ws + 96468992);                    // 16 MB
  unsigned short* OUT1b = (unsigned short*)(ws + 113246208);  // 8 MB
  unsigned short* Wqkv_t = (unsigned short*)(ws + 121634816); // 6 MB
  unsigned short* Wr_t = (unsigned short*)(ws + 127926272);   // 2 MB
  unsigned short* Wo_t = (unsigned short*)(ws + 130023424);   // 2 MB
  unsigned short* Wff1_t = (unsigned short*)(ws + 132120576); // 8 MB
  unsigned short* Wff2_t = (unsigned short*)(ws + 140509184); // 8 MB
  unsigned short* Catb = (unsigned short*)(ws + 79691776);    // aliases X1
  unsigned short* Posb = (unsigned short*)(ws + 96468992);    // aliases OUT1
  unsigned short* H = (unsigned short*)(ws + 0);              // aliases QQ/QK/Kb
  float* C2 = X1;

  const dim3 blk(256);

  cvt_bf16_kernel<<<4096, blk, 0, stream>>>(memories, Catb);
  cvt_bf16_kernel<<<4096, blk, 0, stream>>>(word_embed, Catb + (size_t)4096 * 1024);
  cvt_bf16_kernel<<<2048, blk, 0, stream>>>(pos_embed, Posb);

  transpose_to_bf16<float><<<dim3(48, 16, 1), blk, 0, stream>>>(W_qkv, Wqkv_t, 1024, 3072);
  transpose_to_bf16<float><<<dim3(16, 16, 1), blk, 0, stream>>>(W_r, Wr_t, 1024, 1024);
  transpose_to_bf16<float><<<dim3(16, 16, 1), blk, 0, stream>>>(W_o, Wo_t, 1024, 1024);
  transpose_to_bf16<float><<<dim3(64, 16, 1), blk, 0, stream>>>(W_ff1, Wff1_t, 1024, 4096);
  transpose_to_bf16<float><<<dim3(16, 64, 1), blk, 0, stream>>>(W_ff2, Wff2_t, 4096, 1024);

  {
    GemmArgs a{};
    a.A = Catb;
    a.row_split = 4096;
    a.Bt = Wqkv_t;
    a.M = 8192; a.N = 3072; a.K = 1024;
    a.p0 = bias_q; a.p1 = bias_k;
    a.o0 = QQ; a.o1 = QK; a.o2 = Kb; a.o3 = Vb;
    gemm_kernel<0><<<dim3(24, 64), blk, 0, stream>>>(a);
  }
  {
    GemmArgs a{};
    a.A = Posb;
    a.Bt = Wr_t;
    a.M = 2048; a.N = 1024; a.K = 1024;
    a.o0 = Rb;
    gemm_kernel<1><<<dim3(8, 16), blk, 0, stream>>>(a);
  }
  transpose_to_bf16<unsigned short><<<dim3(1, 32, 64), blk, 0, stream>>>(Vb, Vt, 2048, 64);

  // attention: 8 i-tiles of 128 x 64 (b,n)
  attn_kernel<<<dim3(8, 64), blk, 0, stream>>>(QQ, QK, Kb, Vt, Rb, AVb);

  {
    GemmArgs a{};
    a.A = AVb;
    a.Bt = Wo_t;
    a.M = 4096; a.N = 1024; a.K = 1024;
    a.resid = word_embed;
    a.outF = X1;
    gemm_kernel<2><<<dim3(8, 32), blk, 0, stream>>>(a);
  }
  ln_kernel<<<4096, blk, 0, stream>>>(X1, ln1_g, ln1_b, OUT1, OUT1b);

  {
    GemmArgs a{};
    a.A = OUT1b;
    a.Bt = Wff1_t;
    a.M = 4096; a.N = 4096; a.K = 1024;
    a.p0 = b_ff1;
    a.relu = 1;
    a.o0 = H;
    gemm_kernel<2><<<dim3(32, 32), blk, 0, stream>>>(a);
  }
  {
    GemmArgs a{};
    a.A = H;
    a.Bt = Wff2_t;
    a.M = 4096; a.N = 1024; a.K = 4096;
    a.p0 = b_ff2;
    a.resid = OUT1;
    a.outF = C2;
    gemm_kernel<2><<<dim3(8, 32), blk, 0, stream>>>(a);
  }
  ln_kernel<<<4096, blk, 0, stream>>>(C2, ln2_g, ln2_b, out, nullptr);
}

// Round 6
// 666.012 us; speedup vs baseline: 1.3750x; 1.1070x over previous
//
#include <hip/hip_runtime.h>

// ---------------------------------------------------------------------------
// Transformer-XL decoder layer on MI355X (gfx950).
// QLEN=1024, MLEN=1024, KLEN=2048, BSZ=4, DMODEL=1024, NHEAD=16, DHEAD=64, DFF=4096
// Round 6: attention v6 -- barrier-free, 4 blocks/CU. K/V/R are stored in
// MFMA *fragment-major* layout by the GEMM epilogues (each 16-col B-fragment
// = contiguous 1 KB ordered lane*16B), so attention B-operands are single
// coalesced dwordx4 loads from L2-resident slabs. Only the P C->A-layout hop
// uses wave-private LDS (17 KB). Grid (bn, itile) so block%8 == bn%8 keeps
// each XCD's working set at 8 slabs (~6 MB).
// rel_shift fact: BD[i,j] = BDu[i, j+1023-i] for j <= i+1024; rest is masked.
// ---------------------------------------------------------------------------

typedef __bf16 bf16x8 __attribute__((ext_vector_type(8)));
typedef float f32x4 __attribute__((ext_vector_type(4)));

#define DEVI __device__ __forceinline__

DEVI unsigned short f2bf(float f) {
  union { float f; unsigned int u; } v;
  v.f = f;
  unsigned int u = v.u;
  u += 0x7fffu + ((u >> 16) & 1u);  // RNE
  return (unsigned short)(u >> 16);
}

// async global->LDS, 16 B per lane; lds dest is the wave-uniform base.
DEVI void load16(const unsigned short* g, unsigned short* l) {
  __builtin_amdgcn_global_load_lds(
      (const __attribute__((address_space(1))) unsigned int*)g,
      (__attribute__((address_space(3))) unsigned int*)l, 16, 0, 0);
}

// ---------------------------------------------------------------------------
// f32 -> bf16 elementwise convert (grid covers exactly n/4 float4 groups)
// ---------------------------------------------------------------------------
__global__ __launch_bounds__(256) void cvt_bf16_kernel(const float* __restrict__ in,
                                                       unsigned short* __restrict__ out) {
  const int i = blockIdx.x * 256 + threadIdx.x;
  float4 v = *(const float4*)(in + (size_t)i * 4);
  ushort4 o;
  o.x = f2bf(v.x);
  o.y = f2bf(v.y);
  o.z = f2bf(v.z);
  o.w = f2bf(v.w);
  *(ushort4*)(out + (size_t)i * 4) = o;
}

// ---------------------------------------------------------------------------
// transpose + convert to bf16: out[c][r] = bf16(in[r][c])
// ---------------------------------------------------------------------------
template <typename T>
__global__ __launch_bounds__(256) void transpose_to_bf16(
    const T* __restrict__ in, unsigned short* __restrict__ out, int R, int C) {
  __shared__ unsigned short t[64][72];
  const int tid = threadIdx.x;
  const size_t zoff = (size_t)blockIdx.z * R * C;
  const int r0 = blockIdx.y * 64, c0 = blockIdx.x * 64;
  const T* inp = in + zoff;
  unsigned short* outp = out + zoff;
#pragma unroll
  for (int it = 0; it < 4; ++it) {
    int f = tid + 256 * it;
    int r = f >> 4;
    int c4 = (f & 15) << 2;
    if constexpr (sizeof(T) == 4) {
      float4 v = *(const float4*)((const float*)inp + (size_t)(r0 + r) * C + c0 + c4);
      t[c4 + 0][r] = f2bf(v.x);
      t[c4 + 1][r] = f2bf(v.y);
      t[c4 + 2][r] = f2bf(v.z);
      t[c4 + 3][r] = f2bf(v.w);
    } else {
      ushort4 v = *(const ushort4*)((const unsigned short*)inp + (size_t)(r0 + r) * C + c0 + c4);
      t[c4 + 0][r] = v.x;
      t[c4 + 1][r] = v.y;
      t[c4 + 2][r] = v.z;
      t[c4 + 3][r] = v.w;
    }
  }
  __syncthreads();
#pragma unroll
  for (int it = 0; it < 4; ++it) {
    int f = tid + 256 * it;
    int cc = f >> 4;
    int r4 = (f & 15) << 2;
    ushort4 o;
    o.x = t[cc][r4 + 0];
    o.y = t[cc][r4 + 1];
    o.z = t[cc][r4 + 2];
    o.w = t[cc][r4 + 3];
    *(ushort4*)(outp + (size_t)(c0 + cc) * R + r0 + r4) = o;
  }
}

// ---------------------------------------------------------------------------
// 128x128x64 MFMA GEMM, global_load_lds staging (unchanged from R3).
// EPI 0: QKV scatter (K/V to fragment-major); EPI 1: R scatter (frag-major);
// EPI 2: bias/resid/relu -> f32/bf16.
// Fragment-major layout (per 64-row slab, stride 131072 shorts):
//   AC/BD-type: idx = (t16*2+half)*512 + (quad*16+l15)*8 + e
//               value = X[row=t16*16+l15][col=half*32+quad*8+e]
//   PV-type V:  idx = jt*8192 + (ks*4+nto)*512 + (quad*16+l15)*8 + e
//               value = V[j=jt*128+ks*32+quad*8+e][d=nto*16+l15]
// ---------------------------------------------------------------------------
struct GemmArgs {
  const unsigned short* A;   // bf16 [M][K]
  const unsigned short* Bt;  // bf16 [N][K]
  int row_split;             // EPI0: rows below this skip q columns
  int M, N, K;
  const float* p0;  // bias_q (EPI0) / bias (EPI2)
  const float* p1;  // bias_k (EPI0)
  const float* resid;
  float* outF;
  unsigned short* o0;  // QQ / Rf / bf16-out
  unsigned short* o1;  // QK
  unsigned short* o2;  // Kf
  unsigned short* o3;  // Vf
  int relu;
};

constexpr int BM = 128, BN = 128, BK = 64;

template <int EPI>
__global__ __launch_bounds__(256, 4) void gemm_kernel(GemmArgs ga) {
  __shared__ __align__(16) unsigned short As[BM * BK];
  __shared__ __align__(16) unsigned short Bs[BN * BK];

  const int n0 = blockIdx.x * BN;
  const int m0 = blockIdx.y * BM;
  if constexpr (EPI == 0) {
    if (n0 + BN <= 1024 && m0 + BM <= ga.row_split) return;
  }
  const int tid = threadIdx.x;
  const int lane = tid & 63;
  const int wv = tid >> 6;
  const int l15 = lane & 15;
  const int quad = lane >> 4;
  const int wm = wv & 1, wn = wv >> 1;
  const int K = ga.K;
  const int r8 = lane >> 3;
  const int sc = (lane & 7) ^ r8;

  const f32x4 fzero = {0.f, 0.f, 0.f, 0.f};
  f32x4 acc[4][4];
#pragma unroll
  for (int i = 0; i < 4; ++i)
#pragma unroll
    for (int j = 0; j < 4; ++j) acc[i][j] = fzero;

  const unsigned short* Ab = ga.A + (size_t)(m0 + 32 * wv + r8) * K + sc * 8;
  const unsigned short* Bb = ga.Bt + (size_t)(n0 + 32 * wv + r8) * K + sc * 8;
  const int h7 = l15 & 7;

  for (int k0 = 0; k0 < K; k0 += BK) {
    __syncthreads();
#pragma unroll
    for (int it = 0; it < 4; ++it)
      load16(Ab + (size_t)(8 * it) * K + k0, &As[(32 * wv + 8 * it) * 64]);
#pragma unroll
    for (int it = 0; it < 4; ++it)
      load16(Bb + (size_t)(8 * it) * K + k0, &Bs[(32 * wv + 8 * it) * 64]);
    __syncthreads();
#pragma unroll
    for (int ks = 0; ks < 2; ++ks) {
      bf16x8 af[4], bg[4];
#pragma unroll
      for (int mt = 0; mt < 4; ++mt)
        af[mt] = *(const bf16x8*)&As[(wm * 64 + mt * 16 + l15) * 64 +
                                     (((ks * 4 + quad) ^ h7) * 8)];
#pragma unroll
      for (int nt = 0; nt < 4; ++nt)
        bg[nt] = *(const bf16x8*)&Bs[(wn * 64 + nt * 16 + l15) * 64 +
                                     (((ks * 4 + quad) ^ h7) * 8)];
#pragma unroll
      for (int mt = 0; mt < 4; ++mt)
#pragma unroll
        for (int nt = 0; nt < 4; ++nt)
          acc[mt][nt] =
              __builtin_amdgcn_mfma_f32_16x16x32_bf16(af[mt], bg[nt], acc[mt][nt], 0, 0, 0);
    }
  }

#pragma unroll
  for (int mt = 0; mt < 4; ++mt) {
#pragma unroll
    for (int nt = 0; nt < 4; ++nt) {
#pragma unroll
      for (int r = 0; r < 4; ++r) {
        const int row = m0 + wm * 64 + mt * 16 + quad * 4 + r;
        const int col = n0 + wn * 64 + nt * 16 + l15;
        float val = acc[mt][nt][r];
        if constexpr (EPI == 0) {
          const int seq = row >> 2, b = row & 3;  // cat flat row = seq*BSZ + b
          if (col < 1024) {
            if (seq >= 1024) {
              const int nh = col >> 6, d = col & 63;
              const size_t o = ((size_t)((b * 16 + nh) * 1024 + (seq - 1024))) * 64 + d;
              ga.o0[o] = f2bf(val + ga.p0[col]);  // q + bias_q
              ga.o1[o] = f2bf(val + ga.p1[col]);  // q + bias_k
            }
          } else if (col < 2048) {
            // K -> fragment-major
            const int c = col - 1024, nh = c >> 6, d = c & 63, bn = b * 16 + nh;
            const size_t o = (size_t)bn * 131072 +
                             (size_t)(((seq >> 4) * 2 + (d >> 5)) * 512) +
                             ((((d >> 3) & 3) * 16 + (seq & 15)) * 8) + (d & 7);
            ga.o2[o] = f2bf(val);
          } else {
            // V -> fragment-major (PV-type)
            const int c = col - 2048, nh = c >> 6, d = c & 63, bn = b * 16 + nh;
            const size_t o = (size_t)bn * 131072 + (size_t)((seq >> 7) * 8192) +
                             ((((seq >> 5) & 3) * 4 + (d >> 4)) * 512) +
                             ((((seq >> 3) & 3) * 16 + (d & 15)) * 8) + (seq & 7);
            ga.o3[o] = f2bf(val);
          }
        } else if constexpr (EPI == 1) {
          // R -> fragment-major per head
          const int nh = col >> 6, d = col & 63, t = row;
          const size_t o = (size_t)nh * 131072 +
                           (size_t)(((t >> 4) * 2 + (d >> 5)) * 512) +
                           ((((d >> 3) & 3) * 16 + (t & 15)) * 8) + (d & 7);
          ga.o0[o] = f2bf(val);
        } else {
          if (ga.p0) val += ga.p0[col];
          if (ga.resid) val += ga.resid[(size_t)row * ga.N + col];
          if (ga.relu) val = fmaxf(val, 0.f);
          if (ga.outF) ga.outF[(size_t)row * ga.N + col] = val;
          if (ga.o0) ga.o0[(size_t)row * ga.N + col] = f2bf(val);
        }
      }
    }
  }
}

// ---------------------------------------------------------------------------
// Flash attention with Transformer-XL relative-position term (v6).
// Barrier-free; one wave per 16-row i-tile; 4 blocks/CU. All K/V/R B-operands
// are coalesced dwordx4 loads from fragment-major global slabs (L2-resident).
// Fixed-max softmax; l reduced once at epilogue; P hop via wave-private LDS.
// ---------------------------------------------------------------------------
constexpr int P_LD = 136;            // p_s row stride (bf16 elems)
constexpr float CEXP = 0.18033688f;  // 0.125 * log2(e)

__global__ __launch_bounds__(256, 4) void attn_kernel(
    const unsigned short* __restrict__ QQ, const unsigned short* __restrict__ QK,
    const unsigned short* __restrict__ Kf, const unsigned short* __restrict__ Vf,
    const unsigned short* __restrict__ Rf, unsigned short* __restrict__ AVb) {
  __shared__ __align__(16) unsigned short p_s[4][16 * P_LD];

  const int tid = threadIdx.x;
  const int lane = tid & 63;
  const int wv = tid >> 6;
  const int l15 = lane & 15;
  const int quad = lane >> 4;
  const int bn = blockIdx.x;                   // (b,n): block%8 == bn%8 -> XCD locality
  const int iw = (blockIdx.y * 4 + wv) * 16;   // wave-private 16-row i-tile
  const int nh = bn & 15;
  const int bb = bn >> 4;
  unsigned short* pw = &p_s[wv][0];

  const unsigned short* kf = Kf + (size_t)bn * 131072;
  const unsigned short* vf = Vf + (size_t)bn * 131072;
  const unsigned short* rf = Rf + (size_t)nh * 131072;

  // Q fragments in registers: rows [iw, iw+16)
  const size_t qoff = (size_t)bn * (1024 * 64) + (size_t)(iw + l15) * 64;
  const bf16x8 qq0 = *(const bf16x8*)(QQ + qoff + quad * 8);
  const bf16x8 qq1 = *(const bf16x8*)(QQ + qoff + 32 + quad * 8);
  const bf16x8 qk0 = *(const bf16x8*)(QK + qoff + quad * 8);
  const bf16x8 qk1 = *(const bf16x8*)(QK + qoff + 32 + quad * 8);

  const f32x4 fzero = {0.f, 0.f, 0.f, 0.f};
  f32x4 o_acc[4];
#pragma unroll
  for (int i = 0; i < 4; ++i) o_acc[i] = fzero;
  float lsum[4] = {0.f, 0.f, 0.f, 0.f};

  const int lane8 = lane * 8;
  const int jmax = iw + 15 + 1024;  // beyond this, tiles are fully masked
  for (int j0 = 0; j0 <= jmax; j0 += 128) {
    // BDu: window base t16b = (j0 + 1008 - iw)/16; 9 fragment tiles, clamped
    const int t16b = (j0 >> 4) + 63 - (iw >> 4);
    f32x4 bd[9];
#pragma unroll
    for (int ct = 0; ct < 9; ++ct) {
      int tg = t16b + ct;
      tg = (tg < 127) ? tg : 127;  // rows >=2048 only feed masked cols
      const unsigned short* rb = rf + (size_t)(tg * 1024) + lane8;
      bf16x8 b0 = *(const bf16x8*)rb;
      bf16x8 b1 = *(const bf16x8*)(rb + 512);
      f32x4 c = fzero;
      c = __builtin_amdgcn_mfma_f32_16x16x32_bf16(qk0, b0, c, 0, 0, 0);
      c = __builtin_amdgcn_mfma_f32_16x16x32_bf16(qk1, b1, c, 0, 0, 0);
      bd[ct] = c;
    }

    // AC = (q+bias_q) @ K^T
    const int ntb = j0 >> 4;
    f32x4 sv[8];
#pragma unroll
    for (int nt = 0; nt < 8; ++nt) {
      const unsigned short* kb = kf + (size_t)((ntb + nt) * 1024) + lane8;
      bf16x8 b0 = *(const bf16x8*)kb;
      bf16x8 b1 = *(const bf16x8*)(kb + 512);
      f32x4 c = fzero;
      c = __builtin_amdgcn_mfma_f32_16x16x32_bf16(qq0, b0, c, 0, 0, 0);
      c = __builtin_amdgcn_mfma_f32_16x16x32_bf16(qq1, b1, c, 0, 0, 0);
      sv[nt] = c;
    }

    // rel-shift (in-quad rotate) + fixed-max exp + per-lane l accumulation
#pragma unroll
    for (int r = 0; r < 4; ++r) {
      const int il = quad * 4 + r;  // tile-local row
      const int u = l15 + 15 - il;  // 0..30
      const int srcl = (lane & 48) | (u & 15);
      float w[9];
#pragma unroll
      for (int ct = 0; ct < 9; ++ct) w[ct] = __shfl(bd[ct][r], srcl, 64);
      const int ig = iw + il;
#pragma unroll
      for (int nt = 0; nt < 8; ++nt) {
        const float bdv = (u & 16) ? w[nt + 1] : w[nt];
        const int jg = j0 + nt * 16 + l15;
        float p = exp2f((sv[nt][r] + bdv) * CEXP);
        p = (jg > ig + 1024) ? 0.f : p;  // select: garbage/NaN-safe
        lsum[r] += p;
        pw[il * P_LD + nt * 16 + l15] = f2bf(p);
      }
    }

    // O += P @ V (K-dim = 128); V fragments coalesced from global
    const unsigned short* vb = vf + (size_t)((j0 >> 7) * 8192) + lane8;
#pragma unroll
    for (int ks = 0; ks < 4; ++ks) {
      bf16x8 ap = *(const bf16x8*)&pw[l15 * P_LD + ks * 32 + quad * 8];
#pragma unroll
      for (int nto = 0; nto < 4; ++nto) {
        bf16x8 bv = *(const bf16x8*)(vb + (ks * 4 + nto) * 512);
        o_acc[nto] = __builtin_amdgcn_mfma_f32_16x16x32_bf16(ap, bv, o_acc[nto], 0, 0, 0);
      }
    }
  }

  // reduce l across the 16 lanes holding each row, then write O/l
  float linv[4];
#pragma unroll
  for (int r = 0; r < 4; ++r) {
    float l = lsum[r];
    l += __shfl_xor(l, 1, 64);
    l += __shfl_xor(l, 2, 64);
    l += __shfl_xor(l, 4, 64);
    l += __shfl_xor(l, 8, 64);
    linv[r] = 1.f / l;
  }
#pragma unroll
  for (int nto = 0; nto < 4; ++nto) {
#pragma unroll
    for (int r = 0; r < 4; ++r) {
      const int ig = iw + quad * 4 + r;
      const int d = nto * 16 + l15;
      const float val = o_acc[nto][r] * linv[r];
      AVb[(size_t)(ig * 4 + bb) * 1024 + nh * 64 + d] = f2bf(val);
    }
  }
}

// ---------------------------------------------------------------------------
// LayerNorm over rows of 1024; optional f32 and bf16 outputs.
// ---------------------------------------------------------------------------
__global__ __launch_bounds__(256) void ln_kernel(const float* __restrict__ x,
                                                 const float* __restrict__ g,
                                                 const float* __restrict__ bta,
                                                 float* __restrict__ outF,
                                                 unsigned short* __restrict__ outB) {
  const int row = blockIdx.x;
  const int tid = threadIdx.x;
  const float* xr = x + (size_t)row * 1024;
  const float4 v = *(const float4*)(xr + tid * 4);
  float s = v.x + v.y + v.z + v.w;
  float ss = v.x * v.x + v.y * v.y + v.z * v.z + v.w * v.w;
#pragma unroll
  for (int off = 1; off < 64; off <<= 1) {
    s += __shfl_xor(s, off, 64);
    ss += __shfl_xor(ss, off, 64);
  }
  __shared__ float red[8];
  const int wv = tid >> 6;
  if ((tid & 63) == 0) {
    red[wv] = s;
    red[4 + wv] = ss;
  }
  __syncthreads();
  s = red[0] + red[1] + red[2] + red[3];
  ss = red[4] + red[5] + red[6] + red[7];
  const float mu = s * (1.f / 1024.f);
  const float var = ss * (1.f / 1024.f) - mu * mu;
  const float rs = rsqrtf(var + 1e-5f);
  const float vv[4] = {v.x, v.y, v.z, v.w};
#pragma unroll
  for (int u = 0; u < 4; ++u) {
    const int c = tid * 4 + u;
    const float y = (vv[u] - mu) * rs * g[c] + bta[c];
    if (outF) outF[(size_t)row * 1024 + c] = y;
    if (outB) outB[(size_t)row * 1024 + c] = f2bf(y);
  }
}

// ---------------------------------------------------------------------------
extern "C" void kernel_launch(void* const* d_in, const int* in_sizes, int n_in,
                              void* d_out, int out_size, void* d_ws, size_t ws_size,
                              hipStream_t stream) {
  (void)in_sizes; (void)n_in; (void)out_size; (void)ws_size;
  const float* word_embed = (const float*)d_in[0];
  const float* pos_embed = (const float*)d_in[1];
  const float* bias_q = (const float*)d_in[2];
  const float* bias_k = (const float*)d_in[3];
  const float* memories = (const float*)d_in[4];
  const float* W_qkv = (const float*)d_in[5];
  const float* W_r = (const float*)d_in[6];
  const float* W_o = (const float*)d_in[7];
  const float* ln1_g = (const float*)d_in[8];
  const float* ln1_b = (const float*)d_in[9];
  const float* W_ff1 = (const float*)d_in[10];
  const float* b_ff1 = (const float*)d_in[11];
  const float* W_ff2 = (const float*)d_in[12];
  const float* b_ff2 = (const float*)d_in[13];
  const float* ln2_g = (const float*)d_in[14];
  const float* ln2_b = (const float*)d_in[15];
  float* out = (float*)d_out;

  char* ws = (char*)d_ws;
  unsigned short* QQ = (unsigned short*)(ws + 0);           // 8 MB
  unsigned short* QK = (unsigned short*)(ws + 8388608);     // 8 MB
  unsigned short* Kf = (unsigned short*)(ws + 16777216);    // 16 MB (frag-major)
  unsigned short* Vf = (unsigned short*)(ws + 50331648);    // 16 MB (frag-major)
  unsigned short* Rf = (unsigned short*)(ws + 67108864);    // 4 MB (frag-major)
  unsigned short* AVb = (unsigned short*)(ws + 71303168);   // 8 MB
  float* X1 = (float*)(ws + 79691776);                      // 16 MB (also C2)
  float* OUT1 = (float*)(ws + 96468992);                    // 16 MB
  unsigned short* OUT1b = (unsigned short*)(ws + 113246208);  // 8 MB
  unsigned short* Wqkv_t = (unsigned short*)(ws + 121634816); // 6 MB
  unsigned short* Wr_t = (unsigned short*)(ws + 127926272);   // 2 MB
  unsigned short* Wo_t = (unsigned short*)(ws + 130023424);   // 2 MB
  unsigned short* Wff1_t = (unsigned short*)(ws + 132120576); // 8 MB
  unsigned short* Wff2_t = (unsigned short*)(ws + 140509184); // 8 MB
  unsigned short* Catb = (unsigned short*)(ws + 79691776);    // aliases X1
  unsigned short* Posb = (unsigned short*)(ws + 96468992);    // aliases OUT1
  unsigned short* H = (unsigned short*)(ws + 0);              // aliases QQ/QK/Kf
  float* C2 = X1;

  const dim3 blk(256);

  cvt_bf16_kernel<<<4096, blk, 0, stream>>>(memories, Catb);
  cvt_bf16_kernel<<<4096, blk, 0, stream>>>(word_embed, Catb + (size_t)4096 * 1024);
  cvt_bf16_kernel<<<2048, blk, 0, stream>>>(pos_embed, Posb);

  transpose_to_bf16<float><<<dim3(48, 16, 1), blk, 0, stream>>>(W_qkv, Wqkv_t, 1024, 3072);
  transpose_to_bf16<float><<<dim3(16, 16, 1), blk, 0, stream>>>(W_r, Wr_t, 1024, 1024);
  transpose_to_bf16<float><<<dim3(16, 16, 1), blk, 0, stream>>>(W_o, Wo_t, 1024, 1024);
  transpose_to_bf16<float><<<dim3(64, 16, 1), blk, 0, stream>>>(W_ff1, Wff1_t, 1024, 4096);
  transpose_to_bf16<float><<<dim3(16, 64, 1), blk, 0, stream>>>(W_ff2, Wff2_t, 4096, 1024);

  // QKV projection: M=8192, N=3072, K=1024; K/V scattered to fragment-major
  {
    GemmArgs a{};
    a.A = Catb;
    a.row_split = 4096;
    a.Bt = Wqkv_t;
    a.M = 8192; a.N = 3072; a.K = 1024;
    a.p0 = bias_q; a.p1 = bias_k;
    a.o0 = QQ; a.o1 = QK; a.o2 = Kf; a.o3 = Vf;
    gemm_kernel<0><<<dim3(24, 64), blk, 0, stream>>>(a);
  }
  // R projection: M=2048, N=1024, K=1024 -> fragment-major per head
  {
    GemmArgs a{};
    a.A = Posb;
    a.Bt = Wr_t;
    a.M = 2048; a.N = 1024; a.K = 1024;
    a.o0 = Rf;
    gemm_kernel<1><<<dim3(8, 16), blk, 0, stream>>>(a);
  }

  // attention: grid (bn=64, itile=16), 1024 blocks, 4/CU, barrier-free
  attn_kernel<<<dim3(64, 16), blk, 0, stream>>>(QQ, QK, Kf, Vf, Rf, AVb);

  {
    GemmArgs a{};
    a.A = AVb;
    a.Bt = Wo_t;
    a.M = 4096; a.N = 1024; a.K = 1024;
    a.resid = word_embed;
    a.outF = X1;
    gemm_kernel<2><<<dim3(8, 32), blk, 0, stream>>>(a);
  }
  ln_kernel<<<4096, blk, 0, stream>>>(X1, ln1_g, ln1_b, OUT1, OUT1b);

  {
    GemmArgs a{};
    a.A = OUT1b;
    a.Bt = Wff1_t;
    a.M = 4096; a.N = 4096; a.K = 1024;
    a.p0 = b_ff1;
    a.relu = 1;
    a.o0 = H;
    gemm_kernel<2><<<dim3(32, 32), blk, 0, stream>>>(a);
  }
  {
    GemmArgs a{};
    a.A = H;
    a.Bt = Wff2_t;
    a.M = 4096; a.N = 1024; a.K = 4096;
    a.p0 = b_ff2;
    a.resid = OUT1;
    a.outF = C2;
    gemm_kernel<2><<<dim3(8, 32), blk, 0, stream>>>(a);
  }
  ln_kernel<<<4096, blk, 0, stream>>>(C2, ln2_g, ln2_b, out, nullptr);
}